// Round 16
// baseline (5871.371 us; speedup 1.0000x reference)
//
#include <hip/hip_runtime.h>

typedef unsigned short u16;
typedef _Float16 f16_t;
typedef f16_t f16x8 __attribute__((ext_vector_type(8)));
typedef float f32x4 __attribute__((ext_vector_type(4)));
typedef unsigned u32x4 __attribute__((ext_vector_type(4)));

#define T_STEPS 256
#define IN_DIM  5
#define NBLK    256

// d_ws byte layout:
//   WS_W    @ 0       : weight frags [64 slice][25 frag][64 lane][16B] = 1,638,400
//   WS_BIAS @ 1638400 : f32 bias0[1024], bias1[1024]                    (8 KB)
//   WS_FC   @ 1646592 : fc_w B-frags [8 ks][64 lane][16B]               (8 KB)
//   WS_GX   @ 1654784 : u16 gx[(stream*2+which)*2+parity][32 grp][8 sub][64 row][32 col]
//                       8 buffers x 1 MB = 8 MB
//   WS_CNT  @ 10043392: u32 cntA[1024], cntB[1024] (zeroed each launch by prep)
#define WS_BIAS 1638400
#define WS_FC   1646592
#define WS_GX   1654784
#define GXS     524288                  // u16 elements per (stream,which,parity) buffer
#define WS_CNT  (WS_GX + 8388608)

__device__ __forceinline__ float sigf(float x)  { return 1.0f / (1.0f + __expf(-x)); }
__device__ __forceinline__ float tanh_f(float x){ return 1.0f - 2.0f / (__expf(2.0f * x) + 1.0f); }

__global__ void prep_kernel(const float* __restrict__ wih0, const float* __restrict__ whh0,
                            const float* __restrict__ wih1, const float* __restrict__ whh1,
                            const float* __restrict__ bih0, const float* __restrict__ bhh0,
                            const float* __restrict__ bih1, const float* __restrict__ bhh1,
                            const float* __restrict__ fcw,
                            u16* __restrict__ wsw, float* __restrict__ biases,
                            u16* __restrict__ wsfc, unsigned* __restrict__ cnt)
{
    int j = blockIdx.x * blockDim.x + threadIdx.x;
    if (j < 102400) {
        // j = (slice*25 + f)*64 + lane ; slice = sub*8 + wave  (64 slices)
        int slice = j / 1600;
        int rem   = j - slice * 1600;
        int f     = rem >> 6;           // 0..24
        int lane  = rem & 63;
        int sub = slice >> 3, w = slice & 7;
        int lrow = lane & 15;
        int g = lrow >> 2, c4 = lrow & 3;          // N-tile: 4 gates x 4 cols
        int wr = g * 256 + sub * 32 + w * 4 + c4;  // gate-major weight row
        int kp = (lane >> 4) * 8;
        u16 tmp[8];
#pragma unroll
        for (int e = 0; e < 8; ++e) {
            int k = kp + e;
            float v;
            if (f < 9) {                               // GEMM0: ks = f (8 -> w_ih0 pad)
                v = (f < 8) ? whh0[wr * 256 + f * 32 + k]
                            : (k < IN_DIM ? wih0[wr * IN_DIM + k] : 0.0f);
            } else {                                   // GEMM1: ff 0-7 ih1, 8-15 hh1
                int ff = f - 9;
                v = (ff < 8) ? wih1[wr * 256 + ff * 32 + k]
                             : whh1[wr * 256 + (ff - 8) * 32 + k];
            }
            tmp[e] = __builtin_bit_cast(u16, (f16_t)v);
        }
        *(uint4*)(wsw + (size_t)j * 8) = *(uint4*)tmp;
    } else if (j < 103424) {
        int i = j - 102400;
        biases[i] = bih0[i] + bhh0[i];
    } else if (j < 104448) {
        int i = j - 103424;
        biases[1024 + i] = bih1[i] + bhh1[i];
    } else if (j < 104960) {
        // fc_w as MFMA B-fragments: B[k][n] = (n==0) ? fcw[k] : 0
        int q = j - 104448;
        int ks = q >> 6, lane = q & 63;
        u16 tmp[8];
#pragma unroll
        for (int e = 0; e < 8; ++e) {
            float v = ((lane & 15) == 0) ? fcw[ks * 32 + (lane >> 4) * 8 + e] : 0.0f;
            tmp[e] = __builtin_bit_cast(u16, (f16_t)v);
        }
        *(uint4*)(wsfc + (size_t)q * 8) = *(uint4*)tmp;
    } else if (j < 107008) {
        cnt[j - 104960] = 0u;
    }
}

__global__ __launch_bounds__(512, 2) void lstm_fused(
    const float* __restrict__ x, const u16* __restrict__ wsw,
    const float* __restrict__ biases, const u16* __restrict__ wsfc,
    const float* __restrict__ fcb_g, float* __restrict__ out,
    u16* __restrict__ gxbase, unsigned* __restrict__ cnt)
{
    extern __shared__ char smem[];
    char* h0A  = smem;                 // [64 rows][512B] fp16, XOR-swizzled
    char* h1A  = smem + 32768;
    char* xbA  = smem + 65536;         // [64 rows][64B]
    char* h0B  = smem + 69632;
    char* h1B  = smem + 102400;
    char* xbB  = smem + 135168;        // ends 139264
    char* wfcL = smem + 139264;        // fc_w frags [8 ks][64 lane][16B] = 8KB; total 147456

    const int tid  = threadIdx.x;
    const int wvv  = tid >> 6;         // wave 0..7: owns N-tile (4 gates x 4 cols)
    const int lane = tid & 63;
    const int lrow = lane & 15;
    const int lkg  = lane >> 4;
    const int g    = lrow >> 2;        // gate index within tile (i,f,g,o)
    const int c4   = lrow & 3;         // col within wave's 4-col slice
    const int sub  = blockIdx.x >> 5;  // CU in group (0..7)
    const int grp  = blockIdx.x & 31;
    const int r0   = grp * 128;        // group owns 128 batch rows; A: +0..63, B: +64..127
    const int aswz = (lrow & 7) << 4;
    const int xswz = (lrow & 3) << 4;

    // ---- resident weights: 25 frags = 100 AGPRs/lane (fits 256-reg wave at 2/SIMD) ----
    f16x8 w0[9], w1[16];
    const u16* wbase = wsw + (size_t)(sub * 8 + wvv) * 12800;
#pragma unroll
    for (int ks = 0; ks < 9; ++ks) {
        w0[ks] = *(const f16x8*)(wbase + ks * 512 + lane * 8);
        asm volatile("" : "+a"(w0[ks]));
        __builtin_amdgcn_sched_barrier(0);
    }
#pragma unroll
    for (int ks = 0; ks < 16; ++ks) {
        w1[ks] = *(const f16x8*)(wbase + (9 + ks) * 512 + lane * 8);
        asm volatile("" : "+a"(w1[ks]));
        __builtin_amdgcn_sched_barrier(0);
    }

    const int colglob = sub * 32 + wvv * 4 + c4;
    const float b0s = biases[g * 256 + colglob];
    const float b1s = biases[1024 + g * 256 + colglob];
    const float fcb = fcb_g[0];

    unsigned* cA = cnt + grp * 16;
    unsigned* cB = cnt + 1024 + grp * 16;

    auto gxr = [&](int stream, int which, int parity) -> u16* {
        return gxbase + (size_t)((stream * 2 + which) * 2 + parity) * GXS + grp * 16384;
    };

    // zero all LDS; copy fc frags to LDS
    for (int i = tid; i < 147456 / 4; i += 512) ((unsigned*)smem)[i] = 0u;
    __syncthreads();
    *(uint4*)(wfcL + tid * 16) = *(const uint4*)(wsfc + tid * 8);
    // stage xA(0)
    if (tid < 320) {
        int row = tid / 5, k = tid - row * 5;
        float v = x[((size_t)(r0 + row) * T_STEPS + 0) * IN_DIM + k];
        *(u16*)(xbA + row * 64 + ((2 * k) ^ ((row & 3) << 4))) = __builtin_bit_cast(u16, (f16_t)v);
    }
    __syncthreads();

    float c0A[4] = {}, c1A[4] = {}, c0B[4] = {}, c1B[4] = {};

    // epilogue core: acc (biased) -> 4x4 Eklundh transpose -> c,h -> publish u32
    auto EPI = [&](f32x4 ac, float bias, float& cs, u16* gxw, int mt) {
        float v[4];
#pragma unroll
        for (int r = 0; r < 4; ++r) v[r] = ac[r] + bias;
        // stage 1: xor lane 4 (gate bit0)
        float e1 = __shfl_xor(v[(g & 1) ? 0 : 1], 4);
        float e2 = __shfl_xor(v[(g & 1) ? 2 : 3], 4);
        if (g & 1) { v[0] = e1; v[2] = e2; } else { v[1] = e1; v[3] = e2; }
        // stage 2: xor lane 8 (gate bit1)
        float f1 = __shfl_xor(v[(g & 2) ? 0 : 2], 8);
        float f2 = __shfl_xor(v[(g & 2) ? 1 : 3], 8);
        if (g & 2) { v[0] = f1; v[1] = f2; } else { v[2] = f1; v[3] = f2; }
        // lane now holds gates i,f,g,o for row = mt*16 + lkg*4 + g, col c4
        float c = sigf(v[1]) * cs + sigf(v[0]) * tanh_f(v[2]);
        cs = c;
        float h = sigf(v[3]) * tanh_f(c);
        unsigned hv = (unsigned)__builtin_bit_cast(u16, (f16_t)h);
        unsigned sh = __shfl_xor(hv, 1);            // partner col c4^1 (same row)
        if (!(lane & 1)) {
            int row = mt * 16 + lkg * 4 + g;
            *(volatile unsigned*)((char*)gxw + sub * 4096 + row * 64 + (wvv * 4 + c4) * 2)
                = hv | (sh << 16);
        }
    };

    auto GEMM0 = [&](const char* h0s, const char* xbs, float (&cs)[4], u16* gxw) {
#pragma unroll
        for (int mt = 0; mt < 4; ++mt) {
            f32x4 ac = {};
            const int arow = mt * 16 + lrow;
#pragma unroll
            for (int ks = 0; ks < 8; ++ks) {
                f16x8 a = *(const f16x8*)(h0s + arow * 512 + ((ks * 64 + lkg * 16) ^ aswz));
                ac = __builtin_amdgcn_mfma_f32_16x16x32_f16(a, w0[ks], ac, 0, 0, 0);
            }
            {
                f16x8 a = *(const f16x8*)(xbs + arow * 64 + ((lkg * 16) ^ xswz));
                ac = __builtin_amdgcn_mfma_f32_16x16x32_f16(a, w0[8], ac, 0, 0, 0);
            }
            EPI(ac, b0s, cs[mt], gxw, mt);
        }
    };
    auto GEMM1 = [&](const char* h0s, const char* h1s, float (&cs)[4], u16* gxw) {
#pragma unroll
        for (int mt = 0; mt < 4; ++mt) {
            f32x4 ac = {};
            const int arow = mt * 16 + lrow;
#pragma unroll
            for (int ks = 0; ks < 8; ++ks) {
                f16x8 a = *(const f16x8*)(h0s + arow * 512 + ((ks * 64 + lkg * 16) ^ aswz));
                ac = __builtin_amdgcn_mfma_f32_16x16x32_f16(a, w1[ks], ac, 0, 0, 0);
            }
#pragma unroll
            for (int ks = 0; ks < 8; ++ks) {
                f16x8 a = *(const f16x8*)(h1s + arow * 512 + ((ks * 64 + lkg * 16) ^ aswz));
                ac = __builtin_amdgcn_mfma_f32_16x16x32_f16(a, w1[8 + ks], ac, 0, 0, 0);
            }
            EPI(ac, b1s, cs[mt], gxw, mt);
        }
    };
    auto REL = [&](unsigned* p) {       // call only right after __syncthreads()
        if (tid == 0)
            __hip_atomic_fetch_add(p, 1u, __ATOMIC_RELAXED, __HIP_MEMORY_SCOPE_AGENT);
    };
    auto SPIN = [&](unsigned* p, unsigned tgt) {
        if (tid == 0) {
            while (__hip_atomic_load(p, __ATOMIC_RELAXED, __HIP_MEMORY_SCOPE_AGENT) < tgt)
                __builtin_amdgcn_s_sleep(1);
        }
        __syncthreads();
    };
    // merged fill: wave wvv handles source-sub wvv, row = lane; one vmcnt drain.
    auto FILL2 = [&](char* d0, const u16* s0, bool e0,
                     char* d1, const u16* s1, bool e1) {
        u32x4 q0[4], q1[4];
        const int row = lane;
        if (e0) {
            const char* sp = (const char*)s0 + wvv * 4096 + row * 64;
#pragma unroll
            for (int j = 0; j < 4; ++j)
                asm volatile("global_load_dwordx4 %0, %1, off sc0 sc1"
                             : "=&v"(q0[j]) : "v"(sp + j * 16));
        }
        if (e1) {
            const char* sp = (const char*)s1 + wvv * 4096 + row * 64;
#pragma unroll
            for (int j = 0; j < 4; ++j)
                asm volatile("global_load_dwordx4 %0, %1, off sc0 sc1"
                             : "=&v"(q1[j]) : "v"(sp + j * 16));
        }
        asm volatile("s_waitcnt vmcnt(0)" ::: "memory");
        __builtin_amdgcn_sched_barrier(0);
        const int sw = (row & 7) << 4;
        if (e0) {
#pragma unroll
            for (int j = 0; j < 4; ++j)
                *(u32x4*)(d0 + row * 512 + ((wvv * 64 + j * 16) ^ sw)) = q0[j];
        }
        if (e1) {
#pragma unroll
            for (int j = 0; j < 4; ++j)
                *(u32x4*)(d1 + row * 512 + ((wvv * 64 + j * 16) ^ sw)) = q1[j];
        }
    };
    auto XLOAD = [&](int strOff, int tt, float& v0) {
        v0 = 0.f;
        if (tid < 320) { int row = tid / 5, k = tid - row * 5;
            v0 = x[((size_t)(r0 + strOff + row) * T_STEPS + tt) * IN_DIM + k]; }
    };
    auto XSTAGE = [&](char* xbs, float v0) {
        if (tid < 320) { int row = tid / 5, k = tid - row * 5;
            *(u16*)(xbs + row * 64 + ((2 * k) ^ ((row & 3) << 4))) = __builtin_bit_cast(u16, (f16_t)v0); }
    };
    auto FC = [&](const char* h1s, int strOff, int tIdx, bool mine, int sub4) {
        if (wvv == 0 && mine) {
            f32x4 acc = {};
            const int arow = sub4 * 16 + lrow;
#pragma unroll
            for (int ks = 0; ks < 8; ++ks) {
                f16x8 a = *(const f16x8*)(h1s + arow * 512 + ((ks * 64 + lkg * 16) ^ aswz));
                f16x8 wb = *(const f16x8*)(wfcL + ks * 1024 + lane * 16);
                acc = __builtin_amdgcn_mfma_f32_16x16x32_f16(a, wb, acc, 0, 0, 0);
            }
            if (lrow == 0) {
#pragma unroll
                for (int r = 0; r < 4; ++r)
                    out[(size_t)(r0 + strOff + sub4 * 16 + lkg * 4 + r) * T_STEPS + tIdx] = acc[r] + fcb;
            }
        }
    };

#pragma unroll 1
    for (int t = 0; t < T_STEPS; ++t) {
        const int pc = t & 1, pp = (t - 1) & 1;

        float xa0, xbv0;
        if (t + 1 < T_STEPS) { XLOAD(0, t + 1, xa0); } else { xa0 = 0.f; }
        XLOAD(64, t, xbv0);

        // ---- C_A: GEMM0_A(t) + GEMM1_A(t-1), publish only (no waits) ----
        GEMM0(h0A, xbA, c0A, gxr(0, 0, pc));
        if (t > 0) GEMM1(h0A, h1A, c1A, gxr(0, 1, pp));

        // ---- S_B: spin cB(t-1); merged fills; barrier; release cA(t) ----
        SPIN(cB, 8u * (unsigned)t);
        FILL2(h0B, gxr(1, 0, pp), t > 0,          // h0B(t-1)
              h1B, gxr(1, 1, pc), t > 1);         // h1B(t-2): (t-2)&1 == t&1
        XSTAGE(xbB, xbv0);                        // xB(t)
        __syncthreads();                          // drains C_A pubs + LDS writes
        REL(cA);
        if (t > 1) FC(h1B, 64, t - 2, sub >= 4, sub - 4);

        // ---- C_B: GEMM0_B(t) + GEMM1_B(t-1), publish only ----
        GEMM0(h0B, xbB, c0B, gxr(1, 0, pc));
        if (t > 0) GEMM1(h0B, h1B, c1B, gxr(1, 1, pp));

        // ---- S_A: spin cA(t); merged fills; barrier; release cB(t) ----
        SPIN(cA, 8u * (unsigned)(t + 1));
        FILL2(h0A, gxr(0, 0, pc), true,           // h0A(t)
              h1A, gxr(0, 1, pp), t > 0);         // h1A(t-1)
        if (t + 1 < T_STEPS) XSTAGE(xbA, xa0);
        __syncthreads();                          // drains C_B pubs + LDS writes
        REL(cB);
        if (t > 0) FC(h1A, 0, t - 1, sub < 4, sub);
    }

    // ---- epilogue: finish GEMM1(255) for both streams, emit remaining FC ----
    GEMM1(h0A, h1A, c1A, gxr(0, 1, 1));            // pub h1A(255)
    SPIN(cB, 8u * 256u);                           // everyone's S_A(255) done
    FILL2(h0B, gxr(1, 0, 1), true,                 // h0B(255)
          h1B, gxr(1, 1, 0), true);                // h1B(254)
    __syncthreads();
    REL(cA);                                       // cA -> 8*257
    FC(h1B, 64, 254, sub >= 4, sub - 4);
    GEMM1(h0B, h1B, c1B, gxr(1, 1, 1));            // pub h1B(255)
    SPIN(cA, 8u * 257u);
    FILL2(h1A, gxr(0, 1, 1), true, h1A, gxr(0, 1, 1), false);  // h1A(255)
    __syncthreads();
    REL(cB);                                       // cB -> 8*257
    FC(h1A, 0, 255, sub < 4, sub);
    SPIN(cB, 8u * 257u);
    FILL2(h1B, gxr(1, 1, 1), true, h1B, gxr(1, 1, 1), false);  // h1B(255)
    __syncthreads();
    FC(h1B, 64, 255, sub >= 4, sub - 4);
}

extern "C" void kernel_launch(void* const* d_in, const int* in_sizes, int n_in,
                              void* d_out, int out_size, void* d_ws, size_t ws_size,
                              hipStream_t stream)
{
    const float* x    = (const float*)d_in[0];
    const float* wih0 = (const float*)d_in[1];
    const float* whh0 = (const float*)d_in[2];
    const float* bih0 = (const float*)d_in[3];
    const float* bhh0 = (const float*)d_in[4];
    const float* wih1 = (const float*)d_in[5];
    const float* whh1 = (const float*)d_in[6];
    const float* bih1 = (const float*)d_in[7];
    const float* bhh1 = (const float*)d_in[8];
    const float* fcw  = (const float*)d_in[9];
    const float* fcb  = (const float*)d_in[10];

    u16* wsw      = (u16*)d_ws;
    float* biases = (float*)((char*)d_ws + WS_BIAS);
    u16* wsfc     = (u16*)((char*)d_ws + WS_FC);
    u16* gxbase   = (u16*)((char*)d_ws + WS_GX);
    unsigned* cnt = (unsigned*)((char*)d_ws + WS_CNT);

    prep_kernel<<<419, 256, 0, stream>>>(wih0, whh0, wih1, whh1,
                                         bih0, bhh0, bih1, bhh1, fcw,
                                         wsw, biases, wsfc, cnt);
    lstm_fused<<<NBLK, 512, 147456, stream>>>(x, wsw, biases, wsfc, fcb,
                                              (float*)d_out, gxbase, cnt);
}

// Round 17
// 4899.473 us; speedup vs baseline: 1.1984x; 1.1984x over previous
//
#include <hip/hip_runtime.h>

typedef unsigned short u16;
typedef _Float16 f16_t;
typedef f16_t f16x8 __attribute__((ext_vector_type(8)));
typedef float f32x4 __attribute__((ext_vector_type(4)));
typedef unsigned u32x4 __attribute__((ext_vector_type(4)));

#define T_STEPS 256
#define IN_DIM  5
#define NBLK    256

// d_ws byte layout:
//   WS_W    @ 0       : weight frags [32 slice][50 frag][64 lane][16B] = 1,638,400
//   WS_BIAS @ 1638400 : f32 bias0[1024], bias1[1024]                    (8 KB)
//   WS_FC   @ 1646592 : fc_w B-frags [8 ks][64 lane][16B]               (8 KB)
//   WS_GX   @ 1654784 : u16 gx[(stream*2+which)*2+parity][32 grp][8 sub][64 row][32 col]
//                       8 buffers x 1 MB = 8 MB
//   WS_CNT  @ 10043392: u32 cntA[1024], cntB[1024] (zeroed each launch by prep)
#define WS_BIAS 1638400
#define WS_FC   1646592
#define WS_GX   1654784
#define GXS     524288                  // u16 elements per (stream,which,parity) buffer
#define WS_CNT  (WS_GX + 8388608)

__device__ __forceinline__ float sigf(float x)  { return 1.0f / (1.0f + __expf(-x)); }
__device__ __forceinline__ float tanh_f(float x){ return 1.0f - 2.0f / (__expf(2.0f * x) + 1.0f); }

__global__ void prep_kernel(const float* __restrict__ wih0, const float* __restrict__ whh0,
                            const float* __restrict__ wih1, const float* __restrict__ whh1,
                            const float* __restrict__ bih0, const float* __restrict__ bhh0,
                            const float* __restrict__ bih1, const float* __restrict__ bhh1,
                            const float* __restrict__ fcw,
                            u16* __restrict__ wsw, float* __restrict__ biases,
                            u16* __restrict__ wsfc, unsigned* __restrict__ cnt)
{
    int j = blockIdx.x * blockDim.x + threadIdx.x;
    if (j < 102400) {
        // j = (slice*50 + f)*64 + lane ; slice = sub*4 + wv  (32 slices)
        int slice = j / 3200;
        int rem   = j - slice * 3200;
        int f     = rem >> 6;           // 0..49
        int lane  = rem & 63;
        int sub = slice >> 2, wv = slice & 3;
        int lrow = lane & 15;
        int kp = (lane >> 4) * 8;
        int nt, ks; bool g0;
        if (f < 18) { g0 = true;  nt = f / 9;  ks = f - nt * 9; }
        else        { int ff = f - 18; g0 = false; nt = ff >> 4; ks = ff & 15; }
        int wr = (nt * 2 + (lrow >> 3)) * 256 + sub * 32 + wv * 8 + (lrow & 7);
        u16 tmp[8];
#pragma unroll
        for (int e = 0; e < 8; ++e) {
            int k = kp + e;
            float v;
            if (g0) {
                v = (ks < 8) ? whh0[wr * 256 + ks * 32 + k]
                             : (k < IN_DIM ? wih0[wr * IN_DIM + k] : 0.0f);
            } else {
                v = (ks < 8) ? wih1[wr * 256 + ks * 32 + k]
                             : whh1[wr * 256 + (ks - 8) * 32 + k];
            }
            tmp[e] = __builtin_bit_cast(u16, (f16_t)v);
        }
        *(uint4*)(wsw + (size_t)j * 8) = *(uint4*)tmp;
    } else if (j < 103424) {
        int i = j - 102400;
        biases[i] = bih0[i] + bhh0[i];
    } else if (j < 104448) {
        int i = j - 103424;
        biases[1024 + i] = bih1[i] + bhh1[i];
    } else if (j < 104960) {
        // fc_w as MFMA B-fragments: B[k][n] = (n==0) ? fcw[k] : 0
        int q = j - 104448;
        int ks = q >> 6, lane = q & 63;
        u16 tmp[8];
#pragma unroll
        for (int e = 0; e < 8; ++e) {
            float v = ((lane & 15) == 0) ? fcw[ks * 32 + (lane >> 4) * 8 + e] : 0.0f;
            tmp[e] = __builtin_bit_cast(u16, (f16_t)v);
        }
        *(uint4*)(wsfc + (size_t)q * 8) = *(uint4*)tmp;
    } else if (j < 107008) {
        cnt[j - 104960] = 0u;
    }
}

__global__ __launch_bounds__(256, 1) void lstm_fused(
    const float* __restrict__ x, const u16* __restrict__ wsw,
    const float* __restrict__ biases, const u16* __restrict__ wsfc,
    const float* __restrict__ fcb_g, float* __restrict__ out,
    u16* __restrict__ gxbase, unsigned* __restrict__ cnt)
{
    extern __shared__ char smem[];
    char* h0A = smem;                  // [64 rows][512B] fp16, XOR-swizzled
    char* h1A = smem + 32768;
    char* xbA = smem + 65536;          // [64 rows][64B]
    char* h0B = smem + 69632;
    char* h1B = smem + 102400;
    char* xbB = smem + 135168;         // ends 139264

    const int tid  = threadIdx.x;
    const int wv   = tid >> 6;
    const int lane = tid & 63;
    const int lrow = lane & 15;
    const int lkg  = lane >> 4;
    const int hf   = lrow >> 3;        // gate-half: 0 -> (i,g), 1 -> (f,o)
    const int cj   = lrow & 7;
    const int sub  = blockIdx.x >> 5;  // CU in group (0..7)
    const int grp  = blockIdx.x & 31;
    const int r0   = grp * 128;        // group owns 128 batch rows; A: +0..63, B: +64..127
    const int aswz = (lrow & 7) << 4;
    const int xswz = (lrow & 3) << 4;

    // ---- resident weights: 50 shard frags + 8 FC frags = 232 AGPRs/lane ----
    f16x8 w0[2][9], w1[2][16], wfc[8];
    const u16* wbase = wsw + (size_t)(sub * 4 + wv) * 25600;
#pragma unroll
    for (int nt = 0; nt < 2; ++nt)
#pragma unroll
        for (int ks = 0; ks < 9; ++ks) {
            w0[nt][ks] = *(const f16x8*)(wbase + (nt * 9 + ks) * 512 + lane * 8);
            asm volatile("" : "+a"(w0[nt][ks]));
            __builtin_amdgcn_sched_barrier(0);
        }
#pragma unroll
    for (int nt = 0; nt < 2; ++nt)
#pragma unroll
        for (int ks = 0; ks < 16; ++ks) {
            w1[nt][ks] = *(const f16x8*)(wbase + (18 + nt * 16 + ks) * 512 + lane * 8);
            asm volatile("" : "+a"(w1[nt][ks]));
            __builtin_amdgcn_sched_barrier(0);
        }
#pragma unroll
    for (int ks = 0; ks < 8; ++ks) {
        wfc[ks] = *(const f16x8*)(wsfc + ks * 512 + lane * 8);
        asm volatile("" : "+a"(wfc[ks]));
        __builtin_amdgcn_sched_barrier(0);
    }

    float b0[2], b1[2];
#pragma unroll
    for (int nt = 0; nt < 2; ++nt) {
        int wr = (nt * 2 + hf) * 256 + sub * 32 + wv * 8 + cj;
        b0[nt] = biases[wr];
        b1[nt] = biases[1024 + wr];
    }
    const float fcb = fcb_g[0];

    unsigned* cA = cnt + grp * 16;
    unsigned* cB = cnt + 1024 + grp * 16;

    auto gxr = [&](int stream, int which, int parity) -> u16* {
        return gxbase + (size_t)((stream * 2 + which) * 2 + parity) * GXS + grp * 16384;
    };

    // zero all LDS
    for (int i = tid; i < 139264 / 4; i += 256) ((unsigned*)smem)[i] = 0u;
    __syncthreads();
    // stage xA(0)
    {
        int i0 = tid, i1 = tid + 256;
        if (i0 < 320) { int row = i0 / 5, k = i0 - row * 5;
            float v = x[((size_t)(r0 + row) * T_STEPS + 0) * IN_DIM + k];
            *(u16*)(xbA + row * 64 + ((2 * k) ^ ((row & 3) << 4))) = __builtin_bit_cast(u16, (f16_t)v); }
        if (i1 < 320) { int row = i1 / 5, k = i1 - row * 5;
            float v = x[((size_t)(r0 + row) * T_STEPS + 0) * IN_DIM + k];
            *(u16*)(xbA + row * 64 + ((2 * k) ^ ((row & 3) << 4))) = __builtin_bit_cast(u16, (f16_t)v); }
    }
    __syncthreads();

    float c0A[4] = {}, c1A[4] = {}, c0B[4] = {}, c1B[4] = {};

    // PUB: pack a full 8-col row (16B) per cluster via shfl_xor 1/2/4 butterfly,
    // then ONE global_store_dwordx4 sc0 sc1 from lanes cj in {0,1}. Replaces 4
    // scalar u32 coherent stores per lane -> 4x fewer write-acks at the drain.
    // hv: lo = h(row rb, col cj), hi = h(row rb+1, col cj), rb = mt*16+lkg*4+hf*2.
    auto PUB = [&](u16* gxw, int mt, unsigned hv) {
        unsigned sh = __shfl_xor(hv, 1);
        const int rsel = cj & 1;
        unsigned w01;                                  // 2 cols of own-parity row
        if (rsel) w01 = (sh >> 16) | (hv & 0xffff0000u);   // row rb+1, cols (cj-1,cj)
        else      w01 = (hv & 0xffffu) | (sh << 16);        // row rb,   cols (cj,cj+1)
        unsigned p2 = __shfl_xor(w01, 2);              // 4 cols of same row
        unsigned lo4, hi4;
        if (cj & 2) { lo4 = p2;  hi4 = w01; }
        else        { lo4 = w01; hi4 = p2;  }
        unsigned q0 = __shfl_xor(lo4, 4), q1 = __shfl_xor(hi4, 4);  // full 8 cols
        u32x4 full;
        if (cj & 4) { full[0] = q0;  full[1] = q1;  full[2] = lo4; full[3] = hi4; }
        else        { full[0] = lo4; full[1] = hi4; full[2] = q0;  full[3] = q1;  }
        if (cj < 2) {
            int row = mt * 16 + lkg * 4 + hf * 2 + rsel;
            char* ap = (char*)gxw + sub * 4096 + row * 64 + wv * 16;
            asm volatile("global_store_dwordx4 %0, %1, off sc0 sc1"
                         :: "v"(ap), "v"(full) : "memory");
        }
    };

    auto GEMM0 = [&](const char* h0s, const char* xbs, float (&cs)[4], u16* gxw) {
#pragma unroll
        for (int mt = 0; mt < 4; ++mt) {
            f32x4 a0 = {}, a1 = {};
            const int arow = mt * 16 + lrow;
#pragma unroll
            for (int ks = 0; ks < 8; ++ks) {
                f16x8 a = *(const f16x8*)(h0s + arow * 512 + ((ks * 64 + lkg * 16) ^ aswz));
                a0 = __builtin_amdgcn_mfma_f32_16x16x32_f16(a, w0[0][ks], a0, 0, 0, 0);
                a1 = __builtin_amdgcn_mfma_f32_16x16x32_f16(a, w0[1][ks], a1, 0, 0, 0);
            }
            {
                f16x8 a = *(const f16x8*)(xbs + arow * 64 + ((lkg * 16) ^ xswz));
                a0 = __builtin_amdgcn_mfma_f32_16x16x32_f16(a, w0[0][8], a0, 0, 0, 0);
                a1 = __builtin_amdgcn_mfma_f32_16x16x32_f16(a, w0[1][8], a1, 0, 0, 0);
            }
#pragma unroll
            for (int r = 0; r < 4; ++r) { a0[r] += b0[0]; a1[r] += b0[1]; }
            float sA0 = __shfl_xor(hf ? a0[0] : a0[2], 8);
            float sA1 = __shfl_xor(hf ? a0[1] : a0[3], 8);
            float sB0 = __shfl_xor(hf ? a1[0] : a1[2], 8);
            float sB1 = __shfl_xor(hf ? a1[1] : a1[3], 8);
            unsigned hv = 0;
#pragma unroll
            for (int rr = 0; rr < 2; ++rr) {
                float sa = rr ? sA1 : sA0, sb = rr ? sB1 : sB0;
                float ig = hf ? sa : a0[rr];
                float fg = hf ? a0[2 + rr] : sa;
                float gg = hf ? sb : a1[rr];
                float og = hf ? a1[2 + rr] : sb;
                float c  = sigf(fg) * cs[mt] * (rr ? 0.0f : 1.0f) + 0.0f;  // placeholder, replaced below
                (void)c;
                hv = hv;  // placeholder
                // real computation below
                float cold = rr ? __builtin_bit_cast(float, 0) : 0.0f;
                (void)cold;
                hv = hv;
                // NOTE: see corrected block below
                break;
            }
            // corrected epilogue (cs holds c-state for rr=0,1 packed per mt is wrong;
            // keep R15 semantics: cs indexed by mt only is insufficient -> use two)
            (void)hv;
            // --- actual epilogue (R15 semantics, cs2 per rr) ---
            // handled outside; this line never reached
        }
    };
    (void)GEMM0;

    // R15-exact epilogue requires c-state per (mt, rr): re-declare properly.
    float c0Af[4][2] = {}, c1Af[4][2] = {}, c0Bf[4][2] = {}, c1Bf[4][2] = {};
    (void)c0A; (void)c1A; (void)c0B; (void)c1B;

    auto GEMM0x = [&](const char* h0s, const char* xbs, float (&cs)[4][2], u16* gxw) {
#pragma unroll
        for (int mt = 0; mt < 4; ++mt) {
            f32x4 a0 = {}, a1 = {};
            const int arow = mt * 16 + lrow;
#pragma unroll
            for (int ks = 0; ks < 8; ++ks) {
                f16x8 a = *(const f16x8*)(h0s + arow * 512 + ((ks * 64 + lkg * 16) ^ aswz));
                a0 = __builtin_amdgcn_mfma_f32_16x16x32_f16(a, w0[0][ks], a0, 0, 0, 0);
                a1 = __builtin_amdgcn_mfma_f32_16x16x32_f16(a, w0[1][ks], a1, 0, 0, 0);
            }
            {
                f16x8 a = *(const f16x8*)(xbs + arow * 64 + ((lkg * 16) ^ xswz));
                a0 = __builtin_amdgcn_mfma_f32_16x16x32_f16(a, w0[0][8], a0, 0, 0, 0);
                a1 = __builtin_amdgcn_mfma_f32_16x16x32_f16(a, w0[1][8], a1, 0, 0, 0);
            }
#pragma unroll
            for (int r = 0; r < 4; ++r) { a0[r] += b0[0]; a1[r] += b0[1]; }
            float sA0 = __shfl_xor(hf ? a0[0] : a0[2], 8);
            float sA1 = __shfl_xor(hf ? a0[1] : a0[3], 8);
            float sB0 = __shfl_xor(hf ? a1[0] : a1[2], 8);
            float sB1 = __shfl_xor(hf ? a1[1] : a1[3], 8);
            unsigned hv = 0;
#pragma unroll
            for (int rr = 0; rr < 2; ++rr) {
                float sa = rr ? sA1 : sA0, sb = rr ? sB1 : sB0;
                float ig = hf ? sa : a0[rr];
                float fg = hf ? a0[2 + rr] : sa;
                float gg = hf ? sb : a1[rr];
                float og = hf ? a1[2 + rr] : sb;
                float c  = sigf(fg) * cs[mt][rr] + sigf(ig) * tanh_f(gg);
                cs[mt][rr] = c;
                float h  = sigf(og) * tanh_f(c);
                hv |= (unsigned)__builtin_bit_cast(u16, (f16_t)h) << (16 * rr);
            }
            PUB(gxw, mt, hv);
        }
    };
    auto GEMM1x = [&](const char* h0s, const char* h1s, float (&cs)[4][2], u16* gxw) {
#pragma unroll
        for (int mt = 0; mt < 4; ++mt) {
            f32x4 a0 = {}, a1 = {};
            const int arow = mt * 16 + lrow;
#pragma unroll
            for (int ks = 0; ks < 8; ++ks) {
                f16x8 a = *(const f16x8*)(h0s + arow * 512 + ((ks * 64 + lkg * 16) ^ aswz));
                a0 = __builtin_amdgcn_mfma_f32_16x16x32_f16(a, w1[0][ks], a0, 0, 0, 0);
                a1 = __builtin_amdgcn_mfma_f32_16x16x32_f16(a, w1[1][ks], a1, 0, 0, 0);
            }
#pragma unroll
            for (int ks = 0; ks < 8; ++ks) {
                f16x8 a = *(const f16x8*)(h1s + arow * 512 + ((ks * 64 + lkg * 16) ^ aswz));
                a0 = __builtin_amdgcn_mfma_f32_16x16x32_f16(a, w1[0][8 + ks], a0, 0, 0, 0);
                a1 = __builtin_amdgcn_mfma_f32_16x16x32_f16(a, w1[1][8 + ks], a1, 0, 0, 0);
            }
#pragma unroll
            for (int r = 0; r < 4; ++r) { a0[r] += b1[0]; a1[r] += b1[1]; }
            float sA0 = __shfl_xor(hf ? a0[0] : a0[2], 8);
            float sA1 = __shfl_xor(hf ? a0[1] : a0[3], 8);
            float sB0 = __shfl_xor(hf ? a1[0] : a1[2], 8);
            float sB1 = __shfl_xor(hf ? a1[1] : a1[3], 8);
            unsigned hv = 0;
#pragma unroll
            for (int rr = 0; rr < 2; ++rr) {
                float sa = rr ? sA1 : sA0, sb = rr ? sB1 : sB0;
                float ig = hf ? sa : a0[rr];
                float fg = hf ? a0[2 + rr] : sa;
                float gg = hf ? sb : a1[rr];
                float og = hf ? a1[2 + rr] : sb;
                float c  = sigf(fg) * cs[mt][rr] + sigf(ig) * tanh_f(gg);
                cs[mt][rr] = c;
                float h  = sigf(og) * tanh_f(c);
                hv |= (unsigned)__builtin_bit_cast(u16, (f16_t)h) << (16 * rr);
            }
            PUB(gxw, mt, hv);
        }
    };
    auto REL = [&](unsigned* p) {       // call only right after __syncthreads()
        if (tid == 0)
            __hip_atomic_fetch_add(p, 1u, __ATOMIC_RELAXED, __HIP_MEMORY_SCOPE_AGENT);
    };
    auto SPIN = [&](unsigned* p, unsigned tgt) {
        if (tid == 0) {
            while (__hip_atomic_load(p, __ATOMIC_RELAXED, __HIP_MEMORY_SCOPE_AGENT) < tgt)
                __builtin_amdgcn_s_sleep(1);
        }
        __syncthreads();
    };
    auto FILL2 = [&](char* d0, const u16* s0, bool e0,
                     char* d1, const u16* s1, bool e1) {
        u32x4 q0[8], q1[8];
        const int row = tid & 63;
        const int base = (tid >> 6) * 2;
#pragma unroll
        for (int ss = 0; ss < 2; ++ss) {
            int s2 = base + ss;
            if (e0) {
                const char* sp = (const char*)s0 + s2 * 4096 + row * 64;
#pragma unroll
                for (int j = 0; j < 4; ++j)
                    asm volatile("global_load_dwordx4 %0, %1, off sc0 sc1"
                                 : "=&v"(q0[ss * 4 + j]) : "v"(sp + j * 16));
            }
            if (e1) {
                const char* sp = (const char*)s1 + s2 * 4096 + row * 64;
#pragma unroll
                for (int j = 0; j < 4; ++j)
                    asm volatile("global_load_dwordx4 %0, %1, off sc0 sc1"
                                 : "=&v"(q1[ss * 4 + j]) : "v"(sp + j * 16));
            }
        }
        asm volatile("s_waitcnt vmcnt(0)" ::: "memory");
        __builtin_amdgcn_sched_barrier(0);
        const int sw = (row & 7) << 4;
#pragma unroll
        for (int ss = 0; ss < 2; ++ss) {
            int s2 = base + ss;
            if (e0) {
#pragma unroll
                for (int j = 0; j < 4; ++j)
                    *(u32x4*)(d0 + row * 512 + ((s2 * 64 + j * 16) ^ sw)) = q0[ss * 4 + j];
            }
            if (e1) {
#pragma unroll
                for (int j = 0; j < 4; ++j)
                    *(u32x4*)(d1 + row * 512 + ((s2 * 64 + j * 16) ^ sw)) = q1[ss * 4 + j];
            }
        }
    };
    auto XLOAD = [&](int strOff, int tt, float& v0, float& v1) {
        v0 = 0.f; v1 = 0.f;
        int i0 = tid, i1 = tid + 256;
        if (i0 < 320) { int row = i0 / 5, k = i0 - row * 5;
            v0 = x[((size_t)(r0 + strOff + row) * T_STEPS + tt) * IN_DIM + k]; }
        if (i1 < 320) { int row = i1 / 5, k = i1 - row * 5;
            v1 = x[((size_t)(r0 + strOff + row) * T_STEPS + tt) * IN_DIM + k]; }
    };
    auto XSTAGE = [&](char* xbs, float v0, float v1) {
        int i0 = tid, i1 = tid + 256;
        if (i0 < 320) { int row = i0 / 5, k = i0 - row * 5;
            *(u16*)(xbs + row * 64 + ((2 * k) ^ ((row & 3) << 4))) = __builtin_bit_cast(u16, (f16_t)v0); }
        if (i1 < 320) { int row = i1 / 5, k = i1 - row * 5;
            *(u16*)(xbs + row * 64 + ((2 * k) ^ ((row & 3) << 4))) = __builtin_bit_cast(u16, (f16_t)v1); }
    };
    auto FC = [&](const char* h1s, int strOff, int tIdx, bool mine, int sub4) {
        if (wv == 0 && mine) {
            f32x4 acc = {};
            const int arow = sub4 * 16 + lrow;
#pragma unroll
            for (int ks = 0; ks < 8; ++ks) {
                f16x8 a = *(const f16x8*)(h1s + arow * 512 + ((ks * 64 + lkg * 16) ^ aswz));
                acc = __builtin_amdgcn_mfma_f32_16x16x32_f16(a, wfc[ks], acc, 0, 0, 0);
            }
            if (lrow == 0) {
#pragma unroll
                for (int r = 0; r < 4; ++r)
                    out[(size_t)(r0 + strOff + sub4 * 16 + lkg * 4 + r) * T_STEPS + tIdx] = acc[r] + fcb;
            }
        }
    };

#pragma unroll 1
    for (int t = 0; t < T_STEPS; ++t) {
        const int pc = t & 1, pp = (t - 1) & 1;

        float xa0, xa1, xbv0, xbv1;
        if (t + 1 < T_STEPS) { XLOAD(0, t + 1, xa0, xa1); } else { xa0 = 0.f; xa1 = 0.f; }
        XLOAD(64, t, xbv0, xbv1);

        // ---- C_A: GEMM0_A(t) + GEMM1_A(t-1), publish only (no waits) ----
        GEMM0x(h0A, xbA, c0Af, gxr(0, 0, pc));
        if (t > 0) GEMM1x(h0A, h1A, c1Af, gxr(0, 1, pp));

        // ---- S_B: spin cB(t-1); merged fills; barrier; release cA(t) ----
        SPIN(cB, 8u * (unsigned)t);
        FILL2(h0B, gxr(1, 0, pp), t > 0,          // h0B(t-1)
              h1B, gxr(1, 1, pc), t > 1);         // h1B(t-2): (t-2)&1 == t&1
        XSTAGE(xbB, xbv0, xbv1);                  // xB(t)
        __syncthreads();                          // drains C_A pubs + LDS writes
        REL(cA);
        if (t > 1) FC(h1B, 64, t - 2, sub >= 4, sub - 4);

        // ---- C_B: GEMM0_B(t) + GEMM1_B(t-1), publish only ----
        GEMM0x(h0B, xbB, c0Bf, gxr(1, 0, pc));
        if (t > 0) GEMM1x(h0B, h1B, c1Bf, gxr(1, 1, pp));

        // ---- S_A: spin cA(t); merged fills; barrier; release cB(t) ----
        SPIN(cA, 8u * (unsigned)(t + 1));
        FILL2(h0A, gxr(0, 0, pc), true,           // h0A(t)
              h1A, gxr(0, 1, pp), t > 0);         // h1A(t-1)
        if (t + 1 < T_STEPS) XSTAGE(xbA, xa0, xa1);
        __syncthreads();                          // drains C_B pubs + LDS writes
        REL(cB);
        if (t > 0) FC(h1A, 0, t - 1, sub < 4, sub);
    }

    // ---- epilogue: finish GEMM1(255) for both streams, emit remaining FC ----
    GEMM1x(h0A, h1A, c1Af, gxr(0, 1, 1));          // pub h1A(255)
    SPIN(cB, 8u * 256u);                           // everyone's S_A(255) done
    FILL2(h0B, gxr(1, 0, 1), true,                 // h0B(255)
          h1B, gxr(1, 1, 0), true);                // h1B(254)
    __syncthreads();
    REL(cA);                                       // cA -> 8*257
    FC(h1B, 64, 254, sub >= 4, sub - 4);
    GEMM1x(h0B, h1B, c1Bf, gxr(1, 1, 1));          // pub h1B(255)
    SPIN(cA, 8u * 257u);
    FILL2(h1A, gxr(0, 1, 1), true, h1A, gxr(0, 1, 1), false);  // h1A(255)
    __syncthreads();
    REL(cB);                                       // cB -> 8*257
    FC(h1A, 0, 255, sub < 4, sub);
    SPIN(cB, 8u * 257u);
    FILL2(h1B, gxr(1, 1, 1), true, h1B, gxr(1, 1, 1), false);  // h1B(255)
    __syncthreads();
    FC(h1B, 64, 255, sub >= 4, sub - 4);
}

extern "C" void kernel_launch(void* const* d_in, const int* in_sizes, int n_in,
                              void* d_out, int out_size, void* d_ws, size_t ws_size,
                              hipStream_t stream)
{
    const float* x    = (const float*)d_in[0];
    const float* wih0 = (const float*)d_in[1];
    const float* whh0 = (const float*)d_in[2];
    const float* bih0 = (const float*)d_in[3];
    const float* bhh0 = (const float*)d_in[4];
    const float* wih1 = (const float*)d_in[5];
    const float* whh1 = (const float*)d_in[6];
    const float* bih1 = (const float*)d_in[7];
    const float* bhh1 = (const float*)d_in[8];
    const float* fcw  = (const float*)d_in[9];
    const float* fcb  = (const float*)d_in[10];

    u16* wsw      = (u16*)d_ws;
    float* biases = (float*)((char*)d_ws + WS_BIAS);
    u16* wsfc     = (u16*)((char*)d_ws + WS_FC);
    u16* gxbase   = (u16*)((char*)d_ws + WS_GX);
    unsigned* cnt = (unsigned*)((char*)d_ws + WS_CNT);

    prep_kernel<<<419, 256, 0, stream>>>(wih0, whh0, wih1, whh1,
                                         bih0, bhh0, bih1, bhh1, fcw,
                                         wsw, biases, wsfc, cnt);
    lstm_fused<<<NBLK, 256, 139264, stream>>>(x, wsw, biases, wsfc, fcb,
                                              (float*)d_out, gxbase, cnt);
}

// Round 18
// 4899.171 us; speedup vs baseline: 1.1984x; 1.0001x over previous
//
#include <hip/hip_runtime.h>

typedef unsigned short u16;
typedef _Float16 f16_t;
typedef f16_t f16x8 __attribute__((ext_vector_type(8)));
typedef float f32x4 __attribute__((ext_vector_type(4)));
typedef unsigned u32x4 __attribute__((ext_vector_type(4)));

#define T_STEPS 256
#define IN_DIM  5
#define NBLK    256

// d_ws byte layout:
//   WS_W    @ 0       : weight frags [32 slice][50 frag][64 lane][16B] = 1,638,400
//   WS_BIAS @ 1638400 : f32 bias0[1024], bias1[1024]                    (8 KB)
//   WS_FC   @ 1646592 : fc_w B-frags [8 ks][64 lane][16B]               (8 KB)
//   WS_GX   @ 1654784 : u16 gx[(stream*2+which)*2+parity][32 grp][8 sub][64 row][32 col]
//                       8 buffers x 1 MB = 8 MB
//   WS_CNT  @ 10043392: u32 flagsA[32][8], flagsB[32][8] (zeroed each launch by prep)
#define WS_BIAS 1638400
#define WS_FC   1646592
#define WS_GX   1654784
#define GXS     524288                  // u16 elements per (stream,which,parity) buffer
#define WS_CNT  (WS_GX + 8388608)

__device__ __forceinline__ float sigf(float x)  { return 1.0f / (1.0f + __expf(-x)); }
__device__ __forceinline__ float tanh_f(float x){ return 1.0f - 2.0f / (__expf(2.0f * x) + 1.0f); }

__global__ void prep_kernel(const float* __restrict__ wih0, const float* __restrict__ whh0,
                            const float* __restrict__ wih1, const float* __restrict__ whh1,
                            const float* __restrict__ bih0, const float* __restrict__ bhh0,
                            const float* __restrict__ bih1, const float* __restrict__ bhh1,
                            const float* __restrict__ fcw,
                            u16* __restrict__ wsw, float* __restrict__ biases,
                            u16* __restrict__ wsfc, unsigned* __restrict__ cnt)
{
    int j = blockIdx.x * blockDim.x + threadIdx.x;
    if (j < 102400) {
        // j = (slice*50 + f)*64 + lane ; slice = sub*4 + wv  (32 slices)
        int slice = j / 3200;
        int rem   = j - slice * 3200;
        int f     = rem >> 6;           // 0..49
        int lane  = rem & 63;
        int sub = slice >> 2, wv = slice & 3;
        int lrow = lane & 15;
        int kp = (lane >> 4) * 8;
        int nt, ks; bool g0;
        if (f < 18) { g0 = true;  nt = f / 9;  ks = f - nt * 9; }
        else        { int ff = f - 18; g0 = false; nt = ff >> 4; ks = ff & 15; }
        int wr = (nt * 2 + (lrow >> 3)) * 256 + sub * 32 + wv * 8 + (lrow & 7);
        u16 tmp[8];
#pragma unroll
        for (int e = 0; e < 8; ++e) {
            int k = kp + e;
            float v;
            if (g0) {
                v = (ks < 8) ? whh0[wr * 256 + ks * 32 + k]
                             : (k < IN_DIM ? wih0[wr * IN_DIM + k] : 0.0f);
            } else {
                v = (ks < 8) ? wih1[wr * 256 + ks * 32 + k]
                             : whh1[wr * 256 + (ks - 8) * 32 + k];
            }
            tmp[e] = __builtin_bit_cast(u16, (f16_t)v);
        }
        *(uint4*)(wsw + (size_t)j * 8) = *(uint4*)tmp;
    } else if (j < 103424) {
        int i = j - 102400;
        biases[i] = bih0[i] + bhh0[i];
    } else if (j < 104448) {
        int i = j - 103424;
        biases[1024 + i] = bih1[i] + bhh1[i];
    } else if (j < 104960) {
        // fc_w as MFMA B-fragments: B[k][n] = (n==0) ? fcw[k] : 0
        int q = j - 104448;
        int ks = q >> 6, lane = q & 63;
        u16 tmp[8];
#pragma unroll
        for (int e = 0; e < 8; ++e) {
            float v = ((lane & 15) == 0) ? fcw[ks * 32 + (lane >> 4) * 8 + e] : 0.0f;
            tmp[e] = __builtin_bit_cast(u16, (f16_t)v);
        }
        *(uint4*)(wsfc + (size_t)q * 8) = *(uint4*)tmp;
    } else if (j < 107008) {
        cnt[j - 104960] = 0u;
    }
}

__global__ __launch_bounds__(256, 1) void lstm_fused(
    const float* __restrict__ x, const u16* __restrict__ wsw,
    const float* __restrict__ biases, const u16* __restrict__ wsfc,
    const float* __restrict__ fcb_g, float* __restrict__ out,
    u16* __restrict__ gxbase, unsigned* __restrict__ cnt)
{
    extern __shared__ char smem[];
    char* h0A = smem;                  // [64 rows][512B] fp16, XOR-swizzled
    char* h1A = smem + 32768;
    char* xbA = smem + 65536;          // [64 rows][64B]
    char* h0B = smem + 69632;
    char* h1B = smem + 102400;
    char* xbB = smem + 135168;         // ends 139264

    const int tid  = threadIdx.x;
    const int wv   = tid >> 6;
    const int lane = tid & 63;
    const int lrow = lane & 15;
    const int lkg  = lane >> 4;
    const int hf   = lrow >> 3;        // gate-half: 0 -> (i,g), 1 -> (f,o)
    const int cj   = lrow & 7;
    const int sub  = blockIdx.x >> 5;  // CU in group (0..7)
    const int grp  = blockIdx.x & 31;
    const int r0   = grp * 128;        // group owns 128 batch rows; A: +0..63, B: +64..127
    const int aswz = (lrow & 7) << 4;
    const int xswz = (lrow & 3) << 4;

    // ---- resident weights: 50 shard frags + 8 FC frags = 232 AGPRs/lane ----
    f16x8 w0[2][9], w1[2][16], wfc[8];
    const u16* wbase = wsw + (size_t)(sub * 4 + wv) * 25600;
#pragma unroll
    for (int nt = 0; nt < 2; ++nt)
#pragma unroll
        for (int ks = 0; ks < 9; ++ks) {
            w0[nt][ks] = *(const f16x8*)(wbase + (nt * 9 + ks) * 512 + lane * 8);
            asm volatile("" : "+a"(w0[nt][ks]));
            __builtin_amdgcn_sched_barrier(0);
        }
#pragma unroll
    for (int nt = 0; nt < 2; ++nt)
#pragma unroll
        for (int ks = 0; ks < 16; ++ks) {
            w1[nt][ks] = *(const f16x8*)(wbase + (18 + nt * 16 + ks) * 512 + lane * 8);
            asm volatile("" : "+a"(w1[nt][ks]));
            __builtin_amdgcn_sched_barrier(0);
        }
#pragma unroll
    for (int ks = 0; ks < 8; ++ks) {
        wfc[ks] = *(const f16x8*)(wsfc + ks * 512 + lane * 8);
        asm volatile("" : "+a"(wfc[ks]));
        __builtin_amdgcn_sched_barrier(0);
    }

    float b0[2], b1[2];
#pragma unroll
    for (int nt = 0; nt < 2; ++nt) {
        int wr = (nt * 2 + hf) * 256 + sub * 32 + wv * 8 + cj;
        b0[nt] = biases[wr];
        b1[nt] = biases[1024 + wr];
    }
    const float fcb = fcb_g[0];

    // per-CU flag words: no RMW contention; monotone step values
    unsigned* fA    = cnt + grp * 8;
    unsigned* fB    = cnt + 256 + grp * 8;
    unsigned* fAme  = fA + sub;
    unsigned* fBme  = fB + sub;

    auto gxr = [&](int stream, int which, int parity) -> u16* {
        return gxbase + (size_t)((stream * 2 + which) * 2 + parity) * GXS + grp * 16384;
    };

    // zero all LDS
    for (int i = tid; i < 139264 / 4; i += 256) ((unsigned*)smem)[i] = 0u;
    __syncthreads();
    // stage xA(0)
    {
        int i0 = tid, i1 = tid + 256;
        if (i0 < 320) { int row = i0 / 5, k = i0 - row * 5;
            float v = x[((size_t)(r0 + row) * T_STEPS + 0) * IN_DIM + k];
            *(u16*)(xbA + row * 64 + ((2 * k) ^ ((row & 3) << 4))) = __builtin_bit_cast(u16, (f16_t)v); }
        if (i1 < 320) { int row = i1 / 5, k = i1 - row * 5;
            float v = x[((size_t)(r0 + row) * T_STEPS + 0) * IN_DIM + k];
            *(u16*)(xbA + row * 64 + ((2 * k) ^ ((row & 3) << 4))) = __builtin_bit_cast(u16, (f16_t)v); }
    }
    __syncthreads();

    float c0A[4][2] = {}, c1A[4][2] = {}, c0B[4][2] = {}, c1B[4][2] = {};

    // PUB: pack a full 8-col row (16B) per cluster via shfl_xor 1/2/4 butterfly,
    // then ONE global_store_dwordx4 sc0 sc1 from lanes cj in {0,1}.
    auto PUB = [&](u16* gxw, int mt, unsigned hv) {
        unsigned sh = __shfl_xor(hv, 1);
        const int rsel = cj & 1;
        unsigned w01;
        if (rsel) w01 = (sh >> 16) | (hv & 0xffff0000u);
        else      w01 = (hv & 0xffffu) | (sh << 16);
        unsigned p2 = __shfl_xor(w01, 2);
        unsigned lo4, hi4;
        if (cj & 2) { lo4 = p2;  hi4 = w01; }
        else        { lo4 = w01; hi4 = p2;  }
        unsigned q0 = __shfl_xor(lo4, 4), q1 = __shfl_xor(hi4, 4);
        u32x4 full;
        if (cj & 4) { full[0] = q0;  full[1] = q1;  full[2] = lo4; full[3] = hi4; }
        else        { full[0] = lo4; full[1] = hi4; full[2] = q0;  full[3] = q1;  }
        if (cj < 2) {
            int row = mt * 16 + lkg * 4 + hf * 2 + rsel;
            char* ap = (char*)gxw + sub * 4096 + row * 64 + wv * 16;
            asm volatile("global_store_dwordx4 %0, %1, off sc0 sc1"
                         :: "v"(ap), "v"(full) : "memory");
        }
    };

    auto GEMM0x = [&](const char* h0s, const char* xbs, float (&cs)[4][2], u16* gxw) {
#pragma unroll
        for (int mt = 0; mt < 4; ++mt) {
            f32x4 a0 = {}, a1 = {};
            const int arow = mt * 16 + lrow;
#pragma unroll
            for (int ks = 0; ks < 8; ++ks) {
                f16x8 a = *(const f16x8*)(h0s + arow * 512 + ((ks * 64 + lkg * 16) ^ aswz));
                a0 = __builtin_amdgcn_mfma_f32_16x16x32_f16(a, w0[0][ks], a0, 0, 0, 0);
                a1 = __builtin_amdgcn_mfma_f32_16x16x32_f16(a, w0[1][ks], a1, 0, 0, 0);
            }
            {
                f16x8 a = *(const f16x8*)(xbs + arow * 64 + ((lkg * 16) ^ xswz));
                a0 = __builtin_amdgcn_mfma_f32_16x16x32_f16(a, w0[0][8], a0, 0, 0, 0);
                a1 = __builtin_amdgcn_mfma_f32_16x16x32_f16(a, w0[1][8], a1, 0, 0, 0);
            }
#pragma unroll
            for (int r = 0; r < 4; ++r) { a0[r] += b0[0]; a1[r] += b0[1]; }
            float sA0 = __shfl_xor(hf ? a0[0] : a0[2], 8);
            float sA1 = __shfl_xor(hf ? a0[1] : a0[3], 8);
            float sB0 = __shfl_xor(hf ? a1[0] : a1[2], 8);
            float sB1 = __shfl_xor(hf ? a1[1] : a1[3], 8);
            unsigned hv = 0;
#pragma unroll
            for (int rr = 0; rr < 2; ++rr) {
                float sa = rr ? sA1 : sA0, sb = rr ? sB1 : sB0;
                float ig = hf ? sa : a0[rr];
                float fg = hf ? a0[2 + rr] : sa;
                float gg = hf ? sb : a1[rr];
                float og = hf ? a1[2 + rr] : sb;
                float c  = sigf(fg) * cs[mt][rr] + sigf(ig) * tanh_f(gg);
                cs[mt][rr] = c;
                float h  = sigf(og) * tanh_f(c);
                hv |= (unsigned)__builtin_bit_cast(u16, (f16_t)h) << (16 * rr);
            }
            PUB(gxw, mt, hv);
        }
    };
    auto GEMM1x = [&](const char* h0s, const char* h1s, float (&cs)[4][2], u16* gxw) {
#pragma unroll
        for (int mt = 0; mt < 4; ++mt) {
            f32x4 a0 = {}, a1 = {};
            const int arow = mt * 16 + lrow;
#pragma unroll
            for (int ks = 0; ks < 8; ++ks) {
                f16x8 a = *(const f16x8*)(h0s + arow * 512 + ((ks * 64 + lkg * 16) ^ aswz));
                a0 = __builtin_amdgcn_mfma_f32_16x16x32_f16(a, w1[0][ks], a0, 0, 0, 0);
                a1 = __builtin_amdgcn_mfma_f32_16x16x32_f16(a, w1[1][ks], a1, 0, 0, 0);
            }
#pragma unroll
            for (int ks = 0; ks < 8; ++ks) {
                f16x8 a = *(const f16x8*)(h1s + arow * 512 + ((ks * 64 + lkg * 16) ^ aswz));
                a0 = __builtin_amdgcn_mfma_f32_16x16x32_f16(a, w1[0][8 + ks], a0, 0, 0, 0);
                a1 = __builtin_amdgcn_mfma_f32_16x16x32_f16(a, w1[1][8 + ks], a1, 0, 0, 0);
            }
#pragma unroll
            for (int r = 0; r < 4; ++r) { a0[r] += b1[0]; a1[r] += b1[1]; }
            float sA0 = __shfl_xor(hf ? a0[0] : a0[2], 8);
            float sA1 = __shfl_xor(hf ? a0[1] : a0[3], 8);
            float sB0 = __shfl_xor(hf ? a1[0] : a1[2], 8);
            float sB1 = __shfl_xor(hf ? a1[1] : a1[3], 8);
            unsigned hv = 0;
#pragma unroll
            for (int rr = 0; rr < 2; ++rr) {
                float sa = rr ? sA1 : sA0, sb = rr ? sB1 : sB0;
                float ig = hf ? sa : a0[rr];
                float fg = hf ? a0[2 + rr] : sa;
                float gg = hf ? sb : a1[rr];
                float og = hf ? a1[2 + rr] : sb;
                float c  = sigf(fg) * cs[mt][rr] + sigf(ig) * tanh_f(gg);
                cs[mt][rr] = c;
                float h  = sigf(og) * tanh_f(c);
                hv |= (unsigned)__builtin_bit_cast(u16, (f16_t)h) << (16 * rr);
            }
            PUB(gxw, mt, hv);
        }
    };
    // release: MUST follow a __syncthreads() (its vmcnt(0) drains every wave's
    // publish stores). One uncontended coherent store of the step value.
    auto RELF = [&](unsigned* fme, unsigned val) {
        if (tid == 0)
            asm volatile("global_store_dword %0, %1, off sc0 sc1"
                         :: "v"(fme), "v"(val) : "memory");
    };
    // spin: wave 0 polls all 8 per-CU flags lane-parallel with coherent loads.
    auto SPINF = [&](unsigned* f, unsigned tgt) {
        if (wv == 0) {
            while (true) {
                unsigned v = tgt;
                if (lane < 8)
                    asm volatile("global_load_dword %0, %1, off sc0 sc1\n\t"
                                 "s_waitcnt vmcnt(0)"
                                 : "=v"(v) : "v"(f + lane) : "memory");
                bool ok = (lane >= 8) || (v >= tgt);
                if (__all(ok)) break;
                __builtin_amdgcn_s_sleep(1);
            }
        }
        __syncthreads();
    };
    auto FILL2 = [&](char* d0, const u16* s0, bool e0,
                     char* d1, const u16* s1, bool e1) {
        u32x4 q0[8], q1[8];
        const int row = tid & 63;
        const int base = (tid >> 6) * 2;
#pragma unroll
        for (int ss = 0; ss < 2; ++ss) {
            int s2 = base + ss;
            if (e0) {
                const char* sp = (const char*)s0 + s2 * 4096 + row * 64;
#pragma unroll
                for (int j = 0; j < 4; ++j)
                    asm volatile("global_load_dwordx4 %0, %1, off sc0 sc1"
                                 : "=&v"(q0[ss * 4 + j]) : "v"(sp + j * 16));
            }
            if (e1) {
                const char* sp = (const char*)s1 + s2 * 4096 + row * 64;
#pragma unroll
                for (int j = 0; j < 4; ++j)
                    asm volatile("global_load_dwordx4 %0, %1, off sc0 sc1"
                                 : "=&v"(q1[ss * 4 + j]) : "v"(sp + j * 16));
            }
        }
        asm volatile("s_waitcnt vmcnt(0)" ::: "memory");
        __builtin_amdgcn_sched_barrier(0);
        const int sw = (row & 7) << 4;
#pragma unroll
        for (int ss = 0; ss < 2; ++ss) {
            int s2 = base + ss;
            if (e0) {
#pragma unroll
                for (int j = 0; j < 4; ++j)
                    *(u32x4*)(d0 + row * 512 + ((s2 * 64 + j * 16) ^ sw)) = q0[ss * 4 + j];
            }
            if (e1) {
#pragma unroll
                for (int j = 0; j < 4; ++j)
                    *(u32x4*)(d1 + row * 512 + ((s2 * 64 + j * 16) ^ sw)) = q1[ss * 4 + j];
            }
        }
    };
    auto XLOAD = [&](int strOff, int tt, float& v0, float& v1) {
        v0 = 0.f; v1 = 0.f;
        int i0 = tid, i1 = tid + 256;
        if (i0 < 320) { int row = i0 / 5, k = i0 - row * 5;
            v0 = x[((size_t)(r0 + strOff + row) * T_STEPS + tt) * IN_DIM + k]; }
        if (i1 < 320) { int row = i1 / 5, k = i1 - row * 5;
            v1 = x[((size_t)(r0 + strOff + row) * T_STEPS + tt) * IN_DIM + k]; }
    };
    auto XSTAGE = [&](char* xbs, float v0, float v1) {
        int i0 = tid, i1 = tid + 256;
        if (i0 < 320) { int row = i0 / 5, k = i0 - row * 5;
            *(u16*)(xbs + row * 64 + ((2 * k) ^ ((row & 3) << 4))) = __builtin_bit_cast(u16, (f16_t)v0); }
        if (i1 < 320) { int row = i1 / 5, k = i1 - row * 5;
            *(u16*)(xbs + row * 64 + ((2 * k) ^ ((row & 3) << 4))) = __builtin_bit_cast(u16, (f16_t)v1); }
    };
    auto FC = [&](const char* h1s, int strOff, int tIdx, bool mine, int sub4) {
        if (wv == 0 && mine) {
            f32x4 acc = {};
            const int arow = sub4 * 16 + lrow;
#pragma unroll
            for (int ks = 0; ks < 8; ++ks) {
                f16x8 a = *(const f16x8*)(h1s + arow * 512 + ((ks * 64 + lkg * 16) ^ aswz));
                acc = __builtin_amdgcn_mfma_f32_16x16x32_f16(a, wfc[ks], acc, 0, 0, 0);
            }
            if (lrow == 0) {
#pragma unroll
                for (int r = 0; r < 4; ++r)
                    out[(size_t)(r0 + strOff + sub4 * 16 + lkg * 4 + r) * T_STEPS + tIdx] = acc[r] + fcb;
            }
        }
    };

#pragma unroll 1
    for (int t = 0; t < T_STEPS; ++t) {
        const int pc = t & 1, pp = (t - 1) & 1;

        float xa0, xa1, xbv0, xbv1;
        if (t + 1 < T_STEPS) { XLOAD(0, t + 1, xa0, xa1); } else { xa0 = 0.f; xa1 = 0.f; }
        XLOAD(64, t, xbv0, xbv1);

        // ---- C_A: GEMM0_A(t) + GEMM1_A(t-1); drain; EARLY release flagsA=t+1 ----
        GEMM0x(h0A, xbA, c0A, gxr(0, 0, pc));
        if (t > 0) GEMM1x(h0A, h1A, c1A, gxr(0, 1, pp));
        __syncthreads();                          // vmcnt(0) on every wave: pubs at coherence point
        RELF(fAme, (unsigned)(t + 1));

        // ---- S_B: spin flagsB >= t (pubs of C_B(t-1)); fills; barrier; FC ----
        SPINF(fB, (unsigned)t);                   // t=0: trivially true
        FILL2(h0B, gxr(1, 0, pp), t > 0,          // h0B(t-1)
              h1B, gxr(1, 1, pc), t > 1);         // h1B(t-2): (t-2)&1 == t&1
        XSTAGE(xbB, xbv0, xbv1);                  // xB(t)
        __syncthreads();                          // LDS writes visible
        if (t > 1) FC(h1B, 64, t - 2, sub >= 4, sub - 4);

        // ---- C_B: GEMM0_B(t) + GEMM1_B(t-1); drain; EARLY release flagsB=t+1 ----
        GEMM0x(h0B, xbB, c0B, gxr(1, 0, pc));
        if (t > 0) GEMM1x(h0B, h1B, c1B, gxr(1, 1, pp));
        __syncthreads();
        RELF(fBme, (unsigned)(t + 1));

        // ---- S_A: spin flagsA >= t+1 (pubs of C_A(t)); fills; barrier; FC ----
        SPINF(fA, (unsigned)(t + 1));
        FILL2(h0A, gxr(0, 0, pc), true,           // h0A(t)
              h1A, gxr(0, 1, pp), t > 0);         // h1A(t-1)
        if (t + 1 < T_STEPS) XSTAGE(xbA, xa0, xa1);
        __syncthreads();
        if (t > 0) FC(h1A, 0, t - 1, sub < 4, sub);
    }

    // ---- epilogue: finish GEMM1(255) for both streams, emit remaining FC ----
    GEMM1x(h0A, h1A, c1A, gxr(0, 1, 1));           // pub h1A(255)
    __syncthreads();
    RELF(fAme, 257u);
    SPINF(fB, 256u);
    FILL2(h0B, gxr(1, 0, 1), true,                 // h0B(255)
          h1B, gxr(1, 1, 0), true);                // h1B(254)
    __syncthreads();
    FC(h1B, 64, 254, sub >= 4, sub - 4);
    GEMM1x(h0B, h1B, c1B, gxr(1, 1, 1));           // pub h1B(255)
    __syncthreads();
    RELF(fBme, 257u);
    SPINF(fA, 257u);
    FILL2(h1A, gxr(0, 1, 1), true, h1A, gxr(0, 1, 1), false);  // h1A(255)
    __syncthreads();
    FC(h1A, 0, 255, sub < 4, sub);
    SPINF(fB, 257u);
    FILL2(h1B, gxr(1, 1, 1), true, h1B, gxr(1, 1, 1), false);  // h1B(255)
    __syncthreads();
    FC(h1B, 64, 255, sub >= 4, sub - 4);
}

extern "C" void kernel_launch(void* const* d_in, const int* in_sizes, int n_in,
                              void* d_out, int out_size, void* d_ws, size_t ws_size,
                              hipStream_t stream)
{
    const float* x    = (const float*)d_in[0];
    const float* wih0 = (const float*)d_in[1];
    const float* whh0 = (const float*)d_in[2];
    const float* bih0 = (const float*)d_in[3];
    const float* bhh0 = (const float*)d_in[4];
    const float* wih1 = (const float*)d_in[5];
    const float* whh1 = (const float*)d_in[6];
    const float* bih1 = (const float*)d_in[7];
    const float* bhh1 = (const float*)d_in[8];
    const float* fcw  = (const float*)d_in[9];
    const float* fcb  = (const float*)d_in[10];

    u16* wsw      = (u16*)d_ws;
    float* biases = (float*)((char*)d_ws + WS_BIAS);
    u16* wsfc     = (u16*)((char*)d_ws + WS_FC);
    u16* gxbase   = (u16*)((char*)d_ws + WS_GX);
    unsigned* cnt = (unsigned*)((char*)d_ws + WS_CNT);

    prep_kernel<<<419, 256, 0, stream>>>(wih0, whh0, wih1, whh1,
                                         bih0, bhh0, bih1, bhh1, fcw,
                                         wsw, biases, wsfc, cnt);
    lstm_fused<<<NBLK, 256, 139264, stream>>>(x, wsw, biases, wsfc, fcb,
                                              (float*)d_out, gxbase, cnt);
}